// Round 17
// baseline (143.767 us; speedup 1.0000x reference)
//
#include <hip/hip_runtime.h>

using u16    = unsigned short;
using u32    = unsigned int;
using f32x4  = __attribute__((ext_vector_type(4))) float;
using f32x16 = __attribute__((ext_vector_type(16))) float;
using bf16x8 = __attribute__((ext_vector_type(8))) __bf16;
using u16x4  = __attribute__((ext_vector_type(4))) u16;
using u16x8  = __attribute__((ext_vector_type(8))) u16;
using u32x2  = __attribute__((ext_vector_type(2))) u32;
using u32x4  = __attribute__((ext_vector_type(4))) u32;
using i32x4  = __attribute__((ext_vector_type(4))) int;

// B=2, S=2048, D=1024, H=16, DK=64, M=B*S=4096.
// Softmax in exp2 domain with FIXED m=0 (normalization cancels exactly).
// KP/VP/MP packed layouts as R5-R16.
// attn R17: HALF-SPLIT s-accumulator (s0/s1 never co-live: acc 64->48 regs,
// V live 32->16, w 16->8) -> fits the (256,3) unified cap of 170 -> 3 waves/SIMD.
// gemm_qkv: R14 (fp32 A via global_load_lds, fragment-read cvt) — best measured.

__device__ __forceinline__ u16 f2bf(float f) {
  union { __bf16 b; u16 u; } c; c.b = (__bf16)f; return c.u;
}

typedef __attribute__((address_space(1))) const void GVoid;
typedef __attribute__((address_space(3))) void LVoid;

__device__ __forceinline__ void gload_lds16(const void* g, void* l) {
  __builtin_amdgcn_global_load_lds((GVoid*)g, (LVoid*)l, 16, 0, 0);
}

// ---------------- fp32 -> bf16 conversion: WEIGHTS ONLY ----------------
__global__ void cvt_w(const float* __restrict__ a, const float* __restrict__ b,
                      const float* __restrict__ c, const float* __restrict__ dd,
                      u16* __restrict__ oa, u16* __restrict__ ob,
                      u16* __restrict__ oc, u16* __restrict__ od) {
  int y = blockIdx.y;
  const float* s = (y == 0) ? a : (y == 1) ? b : (y == 2) ? c : dd;
  u16* d = (y == 0) ? oa : (y == 1) ? ob : (y == 2) ? oc : od;
  int i = blockIdx.x * 256 + threadIdx.x;
  f32x4 v = ((const f32x4*)s)[i];
  u16x4 r;
#pragma unroll
  for (int j = 0; j < 4; ++j) r[j] = f2bf(v[j]);
  ((u16x4*)d)[i] = r;
}

// ---------------- mask bit-pack + transpose: [B,S,S] i32 -> MP[b][kt][q] u32x2 ----------------
__global__ void pack_mask(const int* __restrict__ m, u32* __restrict__ mp) {
  int tid = blockIdx.x * 256 + threadIdx.x;  // 131072 = 2*32*2048
  int q = tid & 2047, kt = (tid >> 11) & 31, b = tid >> 16;
  const i32x4* src = (const i32x4*)(m + ((size_t)(b * 2048 + q)) * 2048 + kt * 64);
  u32 w0 = 0, w1 = 0;
#pragma unroll
  for (int j = 0; j < 8; ++j) {
    i32x4 a = src[j], c = src[j + 8];
#pragma unroll
    for (int e = 0; e < 4; ++e) {
      w0 |= (a[e] != 0 ? 1u : 0u) << (j * 4 + e);
      w1 |= (c[e] != 0 ? 1u : 0u) << (j * 4 + e);
    }
  }
  ((u32x2*)mp)[((size_t)(b * 32 + kt)) * 2048 + q] = u32x2{w0, w1};
}

// ---------------- QKV GEMM (R14): A fp32 via global_load_lds, cvt at fragment read ----------------
__global__ __launch_bounds__(256, 2) void gemm_qkv(const float* __restrict__ Aq,
                                                   const float* __restrict__ Ak,
                                                   const float* __restrict__ Av,
                                                   const u16* __restrict__ Wb,
                                                   u16* __restrict__ out) {
  __shared__ alignas(16) char lds[49152];
  const int t = threadIdx.x;
  const int lane = t & 63, wid = t >> 6;
  const int g = lane >> 4, r16 = lane & 15;
  const int wm = wid >> 1, wn = wid & 1;
  const int m0 = blockIdx.x * 128, n0 = blockIdx.y * 128;
  const int z = blockIdx.z;

  const float* Axf = (z == 0) ? Aq : (z == 1) ? Ak : Av;
  const char* Ab = (const char*)Axf;
  const char* Bb = (const char*)(Wb + (size_t)z * 1048576);
  u16* op = out + (size_t)z * 4194304;
  const float qsc = (z == 0) ? 0.18033688011f : 1.0f;  // 0.125*log2(e) into Q

  f32x4 acc[4][4] = {};

  for (int kk = 0; kk < 1024; kk += 64) {
#pragma unroll
    for (int i = 0; i < 8; ++i) {
      int ci = i * 256 + t;          // 16B slot
      int row = ci >> 4;
      int pc = ci & 15;
      int lc = pc ^ (row & 15);
      gload_lds16(Ab + (size_t)(m0 + row) * 4096 + kk * 4 + lc * 16, lds + ci * 16);
    }
#pragma unroll
    for (int i = 0; i < 4; ++i) {
      int ci = i * 256 + t;
      int row = ci >> 3;
      int cbs = ((ci & 7) << 4) ^ ((row & 7) << 4);
      gload_lds16(Bb + (size_t)(n0 + row) * 2048 + kk * 2 + cbs, lds + 32768 + ci * 16);
    }
    __syncthreads();
#pragma unroll
    for (int kc = 0; kc < 2; ++kc) {
      bf16x8 af[4], bfr[4];
#pragma unroll
      for (int mf = 0; mf < 4; ++mf) {
        int row = wm * 64 + mf * 16 + r16;
        const char* arow = lds + row * 256;
        int x = row & 15;
        int lc0 = 8 * kc + 2 * g;    // logical 16B chunk of k = 32kc+8g
        f32x4 alo = *(const f32x4*)(arow + ((lc0 ^ x) * 16));
        f32x4 ahi = *(const f32x4*)(arow + (((lc0 + 1) ^ x) * 16));
        u16x8 pk;
#pragma unroll
        for (int j = 0; j < 4; ++j) { pk[j] = f2bf(alo[j]); pk[4 + j] = f2bf(ahi[j]); }
        af[mf] = __builtin_bit_cast(bf16x8, pk);
      }
#pragma unroll
      for (int nf = 0; nf < 4; ++nf) {
        int row = wn * 64 + nf * 16 + r16;
        bfr[nf] = *(const bf16x8*)(lds + 32768 + row * 128 +
                                   ((64 * kc + 16 * g) ^ ((row & 7) << 4)));
      }
#pragma unroll
      for (int mf = 0; mf < 4; ++mf)
#pragma unroll
        for (int nf = 0; nf < 4; ++nf)
          acc[mf][nf] = __builtin_amdgcn_mfma_f32_16x16x32_bf16(af[mf], bfr[nf], acc[mf][nf], 0, 0, 0);
    }
    __syncthreads();
  }

#pragma unroll
  for (int mf = 0; mf < 4; ++mf) {
#pragma unroll
    for (int nf = 0; nf < 4; ++nf) {
      int mb = m0 + wm * 64 + mf * 16 + 4 * g;
      int n = n0 + wn * 64 + nf * 16 + r16;
      if (z == 0) {  // Q: [B,H,S,DK] bf16, pre-scaled
        int bb = mb >> 11, h = n >> 6, dk = n & 63;
#pragma unroll
        for (int r = 0; r < 4; ++r) {
          int s2 = (mb + r) & 2047;
          op[((size_t)(bb * 16 + h) * 2048 + s2) * 64 + dk] = f2bf(acc[mf][nf][r] * qsc);
        }
      } else if (z == 1) {  // K packed: KP[bh][kt][half][chunk][l31] x16B
        int h = n >> 6, dk = n & 63;
#pragma unroll
        for (int r = 0; r < 4; ++r) {
          int m = mb + r;
          int bb = m >> 11, s2 = m & 2047;
          size_t off16 = ((((size_t)(bb * 16 + h) * 32 + (s2 >> 6)) * 2 + ((s2 >> 5) & 1)) * 8 +
                          (dk >> 3)) * 32 + (s2 & 31);
          op[off16 * 8 + (dk & 7)] = f2bf(acc[mf][nf][r]);
        }
      } else {  // V packed: VP[bh][kt][chunk][db][l31] x16B
        int bb = mb >> 11, s2 = mb & 2047, h = n >> 6, d = n & 63;
        size_t off16 = ((((size_t)(bb * 16 + h) * 32 + (s2 >> 6)) * 8 + ((s2 & 63) >> 3)) * 2 +
                        (d >> 5)) * 32 + (d & 31);
        u16x4 pv;
#pragma unroll
        for (int r = 0; r < 4; ++r) pv[r] = f2bf(acc[mf][nf][r]);
        *(u16x4*)(op + off16 * 8 + (s2 & 7)) = pv;
      }
    }
  }
}

// ---------------- out-projection GEMM: bf16 A (ctx), fp32 output ----------------
__global__ __launch_bounds__(256, 2) void gemm_out(const u16* __restrict__ X,
                                                   const u16* __restrict__ W,
                                                   float* __restrict__ out) {
  __shared__ alignas(16) char lds[32768];
  const int t = threadIdx.x;
  const int lane = t & 63, wid = t >> 6;
  const int g = lane >> 4, r16 = lane & 15;
  const int wm = wid >> 1, wn = wid & 1;
  const int m0 = blockIdx.x * 128, n0 = blockIdx.y * 128;
  const char* Ab = (const char*)X;
  const char* Bb = (const char*)W;

  f32x4 acc[4][4] = {};

  for (int kk = 0; kk < 1024; kk += 64) {
#pragma unroll
    for (int i = 0; i < 4; ++i) {
      int ci = i * 256 + t;
      int row = ci >> 3;
      int cbs = ((ci & 7) << 4) ^ ((row & 7) << 4);
      gload_lds16(Ab + (size_t)(m0 + row) * 2048 + kk * 2 + cbs, lds + ci * 16);
      gload_lds16(Bb + (size_t)(n0 + row) * 2048 + kk * 2 + cbs, lds + 16384 + ci * 16);
    }
    __syncthreads();
#pragma unroll
    for (int kc = 0; kc < 2; ++kc) {
      bf16x8 af[4], bfr[4];
#pragma unroll
      for (int mf = 0; mf < 4; ++mf) {
        int row = wm * 64 + mf * 16 + r16;
        af[mf] = *(const bf16x8*)(lds + row * 128 + ((64 * kc + 16 * g) ^ ((row & 7) << 4)));
      }
#pragma unroll
      for (int nf = 0; nf < 4; ++nf) {
        int row = wn * 64 + nf * 16 + r16;
        bfr[nf] = *(const bf16x8*)(lds + 16384 + row * 128 + ((64 * kc + 16 * g) ^ ((row & 7) << 4)));
      }
#pragma unroll
      for (int mf = 0; mf < 4; ++mf)
#pragma unroll
        for (int nf = 0; nf < 4; ++nf)
          acc[mf][nf] = __builtin_amdgcn_mfma_f32_16x16x32_bf16(af[mf], bfr[nf], acc[mf][nf], 0, 0, 0);
    }
    __syncthreads();
  }

#pragma unroll
  for (int mf = 0; mf < 4; ++mf)
#pragma unroll
    for (int nf = 0; nf < 4; ++nf) {
      int mb = m0 + wm * 64 + mf * 16 + 4 * g;
      int n = n0 + wn * 64 + nf * 16 + r16;
#pragma unroll
      for (int r = 0; r < 4; ++r) out[(size_t)(mb + r) * 1024 + n] = acc[mf][nf][r];
    }
}

// ---------------- flash attention: half-split s accumulator, 3 waves/SIMD ----------------
struct KF { bf16x8 k0[4], k1[4]; };

__device__ __forceinline__ void loadK(KF& f, const char* p) {
#pragma unroll
  for (int c = 0; c < 4; ++c) {
    f.k0[c] = *(const bf16x8*)(p + c * 1024);
    f.k1[c] = *(const bf16x8*)(p + 4096 + c * 1024);
  }
}

// one k-half (32 rows): QK -> exp2/mask -> cvt -> PV (2 k-slots)
__device__ __forceinline__ void half_pass(const bf16x8 (&qf)[4], const bf16x8 (&kh)[4],
                                          const char* vp0, const char* vp1, int ksbase,
                                          u32 wmask, float (&psx)[4],
                                          f32x16& o0, f32x16& o1) {
  bf16x8 va0 = *(const bf16x8*)(vp0 + (ksbase + 0) * 2048);
  bf16x8 va1 = *(const bf16x8*)(vp0 + (ksbase + 1) * 2048);
  bf16x8 vb0 = *(const bf16x8*)(vp1 + (ksbase + 0) * 2048);
  bf16x8 vb1 = *(const bf16x8*)(vp1 + (ksbase + 1) * 2048);

  f32x16 s = {};
#pragma unroll
  for (int c = 0; c < 4; ++c)
    s = __builtin_amdgcn_mfma_f32_32x32x16_bf16(kh[c], qf[c], s, 0, 0, 0);

#pragma unroll
  for (int r = 0; r < 16; ++r) {
    const int bit = (r & 3) + 8 * (r >> 2);
    float p = __builtin_amdgcn_exp2f(s[r]);
    int sm;
    asm("v_bfe_i32 %0, %1, %2, 1" : "=v"(sm) : "v"(wmask), "i"(bit));
    p = __uint_as_float(__float_as_uint(p) & (u32)sm);
    s[r] = p;
    psx[r & 3] += p;
  }

  u32 w[8];
#pragma unroll
  for (int ss = 0; ss < 2; ++ss) {
    u32 A0, B0, A1, B1;
    asm("v_cvt_pk_bf16_f32 %0, %1, %2" : "=v"(A0) : "v"(s[8*ss+0]), "v"(s[8*ss+1]));
    asm("v_cvt_pk_bf16_f32 %0, %1, %2" : "=v"(B0) : "v"(s[8*ss+2]), "v"(s[8*ss+3]));
    asm("v_cvt_pk_bf16_f32 %0, %1, %2" : "=v"(A1) : "v"(s[8*ss+4]), "v"(s[8*ss+5]));
    asm("v_cvt_pk_bf16_f32 %0, %1, %2" : "=v"(B1) : "v"(s[8*ss+6]), "v"(s[8*ss+7]));
    asm("v_permlane32_swap_b32 %0, %1" : "+v"(A0), "+v"(A1));
    asm("v_permlane32_swap_b32 %0, %1" : "+v"(B0), "+v"(B1));
    w[4*ss+0] = A0; w[4*ss+1] = B0; w[4*ss+2] = A1; w[4*ss+3] = B1;
  }

  bf16x8 pa0 = __builtin_bit_cast(bf16x8, u32x4{w[0], w[1], w[2], w[3]});
  bf16x8 pa1 = __builtin_bit_cast(bf16x8, u32x4{w[4], w[5], w[6], w[7]});
  o0 = __builtin_amdgcn_mfma_f32_32x32x16_bf16(pa0, va0, o0, 0, 0, 0);
  o1 = __builtin_amdgcn_mfma_f32_32x32x16_bf16(pa0, vb0, o1, 0, 0, 0);
  o0 = __builtin_amdgcn_mfma_f32_32x32x16_bf16(pa1, va1, o0, 0, 0, 0);
  o1 = __builtin_amdgcn_mfma_f32_32x32x16_bf16(pa1, vb1, o1, 0, 0, 0);
}

__device__ __forceinline__ void attn_body(const bf16x8 (&qf)[4], KF& cur, KF& nxt,
                                          const char*& kp, const char*& vp0,
                                          const char*& vp1, const u32x2*& mptr,
                                          u32x2& mcur, int hi,
                                          f32x16& o0, f32x16& o1, float& l_run) {
  // prefetch next K + mask (dbuf'd; consumed next body)
  loadK(nxt, kp);
  u32x2 mnext = *mptr;
  kp += 8192; mptr += 2048;
  __builtin_amdgcn_sched_barrier(0);

  float psx[4] = {0.f, 0.f, 0.f, 0.f};
  half_pass(qf, cur.k0, vp0, vp1, 0, mcur.x >> (4 * hi), psx, o0, o1);  // k rows 0..31
  half_pass(qf, cur.k1, vp0, vp1, 2, mcur.y >> (4 * hi), psx, o0, o1);  // k rows 32..63
  l_run += (psx[0] + psx[1]) + (psx[2] + psx[3]);

  vp0 += 8192; vp1 += 8192;
  mcur = mnext;
}

__global__ __launch_bounds__(256, 3) void attn_kern(const u16* __restrict__ Qh,
                                                    const u16* __restrict__ Kh,
                                                    const u16* __restrict__ Vt,
                                                    const u32* __restrict__ mp,
                                                    u16* __restrict__ ctx) {
  __shared__ float cmb[2][32][64];
  __shared__ float cmbl[2][64];
  const int t = threadIdx.x;
  const int wid = t >> 6, lane = t & 63;
  const int qw = wid & 1, kh = wid >> 1;
  const int hi = lane >> 5, l31 = lane & 31;

  const int wg = (blockIdx.x & 7) * 128 + (blockIdx.x >> 3);
  const int qt = wg & 31, bh = wg >> 5;
  const int b = bh >> 4, h = bh & 15;

  const char* qbytes = (const char*)Qh;
  const int qbase = qt * 64 + qw * 32;
  const int qg = qbase + l31;

  bf16x8 qf[4];
#pragma unroll
  for (int c = 0; c < 4; ++c)
    qf[c] = *(const bf16x8*)(qbytes + ((size_t)bh * 2048 + qg) * 128 + 32 * c + 16 * hi);

  const char* kp  = (const char*)Kh + (size_t)bh * 262144 + (size_t)kh * 131072 + hi * 512 + l31 * 16;
  const char* vp0 = (const char*)Vt + (size_t)bh * 262144 + (size_t)kh * 131072 + hi * 1024 + l31 * 16;
  const char* vp1 = vp0 + 512;
  const u32x2* mptr = (const u32x2*)mp + (size_t)b * 65536 + (size_t)kh * 32768 + qg;

  f32x16 o0 = {}, o1 = {};
  float l_run = 0.f;

  KF A, B2;
  loadK(A, kp);
  kp += 8192;
  u32x2 mcur = *mptr;
  mptr += 2048;

#pragma unroll 1
  for (int it = 0; it < 8; ++it) {   // 16 k-tiles per wave (2 bodies/iter)
    attn_body(qf, A, B2, kp, vp0, vp1, mptr, mcur, hi, o0, o1, l_run);
    attn_body(qf, B2, A, kp, vp0, vp1, mptr, mcur, hi, o0, o1, l_run);
  }

  l_run += __shfl_xor(l_run, 32, 64);

  if (kh) {
#pragma unroll
    for (int r = 0; r < 16; ++r) {
      cmb[qw][r][lane]      = o0[r];
      cmb[qw][16 + r][lane] = o1[r];
    }
    cmbl[qw][lane] = l_run;
  }
  __syncthreads();
  if (!kh) {
#pragma unroll
    for (int r = 0; r < 16; ++r) {
      o0[r] += cmb[qw][r][lane];
      o1[r] += cmb[qw][16 + r][lane];
    }
    l_run += cmbl[qw][lane];

    float rl = 1.f / l_run;
#pragma unroll
    for (int r = 0; r < 16; ++r) {
      float rv = __shfl(rl, (r & 3) + 8 * (r >> 2) + 4 * hi, 64);
      int q = qbase + (r & 3) + 8 * (r >> 2) + 4 * hi;
      size_t rowp = ((size_t)b * 2048 + q) * 1024 + h * 64 + l31;
      ctx[rowp]      = f2bf(o0[r] * rv);
      ctx[rowp + 32] = f2bf(o1[r] * rv);
    }
  }
}

// ---------------- launch ----------------
extern "C" void kernel_launch(void* const* d_in, const int* in_sizes, int n_in,
                              void* d_out, int out_size, void* d_ws, size_t ws_size,
                              hipStream_t stream) {
  const float* q  = (const float*)d_in[0];
  const float* k  = (const float*)d_in[1];
  const float* v  = (const float*)d_in[2];
  const int* mask = (const int*)d_in[3];
  const float* Wq = (const float*)d_in[4];
  const float* Wk = (const float*)d_in[5];
  const float* Wv = (const float*)d_in[6];
  const float* Wo = (const float*)d_in[7];

  u16* ws = (u16*)d_ws;
  const size_t NX = (size_t)4096 * 1024;
  const size_t NW = (size_t)1024 * 1024;
  u16* Wqb = ws + 3 * NX;
  u16* Qh  = Wqb + 4 * NW;          // Qh | KP | VP consecutive
  u16* ctx = Qh + 3 * NX;
  u32* mpk = (u32*)ws;              // 1 MB

  cvt_w<<<dim3(1024, 4), 256, 0, stream>>>(Wq, Wk, Wv, Wo,
                                           Wqb, Wqb + NW, Wqb + 2 * NW, Wqb + 3 * NW);
  pack_mask<<<dim3(512), 256, 0, stream>>>(mask, mpk);
  gemm_qkv<<<dim3(32, 8, 3), 256, 0, stream>>>(q, k, v, Wqb, Qh);
  attn_kern<<<dim3(1024), 256, 0, stream>>>(Qh, Qh + NX, Qh + 2 * NX, mpk, ctx);
  gemm_out<<<dim3(32, 8), 256, 0, stream>>>(ctx, Wqb + 3 * NW, (float*)d_out);
}

// Round 18
// 125.893 us; speedup vs baseline: 1.1420x; 1.1420x over previous
//
#include <hip/hip_runtime.h>

using u16    = unsigned short;
using u32    = unsigned int;
using f32x4  = __attribute__((ext_vector_type(4))) float;
using f32x16 = __attribute__((ext_vector_type(16))) float;
using bf16x8 = __attribute__((ext_vector_type(8))) __bf16;
using u16x4  = __attribute__((ext_vector_type(4))) u16;
using u16x8  = __attribute__((ext_vector_type(8))) u16;
using u32x2  = __attribute__((ext_vector_type(2))) u32;
using u32x4  = __attribute__((ext_vector_type(4))) u32;
using i32x4  = __attribute__((ext_vector_type(4))) int;

// B=2, S=2048, D=1024, H=16, DK=64, M=B*S=4096.
// Softmax in exp2 domain with FIXED m=0 (normalization cancels exactly).
// KP/VP/MP packed layouts as R5-R17.
// REGISTER LEDGER: attn body demands ~228 unified -> ONLY (256,2) compiles
// clean (R6/R8/R11/R17: every lower cap spills). attn = 60us at 2 waves/SIMD.
// gemm_qkv demand ~108 unified << 170 cap -> (256,3) is free: 768 blocks =
// 3x256 exactly one pass (was 1.5 passes at 2/CU), +50% latency-hiding waves.

__device__ __forceinline__ u16 f2bf(float f) {
  union { __bf16 b; u16 u; } c; c.b = (__bf16)f; return c.u;
}

typedef __attribute__((address_space(1))) const void GVoid;
typedef __attribute__((address_space(3))) void LVoid;

__device__ __forceinline__ void gload_lds16(const void* g, void* l) {
  __builtin_amdgcn_global_load_lds((GVoid*)g, (LVoid*)l, 16, 0, 0);
}

// ---------------- fp32 -> bf16 conversion: WEIGHTS ONLY ----------------
__global__ void cvt_w(const float* __restrict__ a, const float* __restrict__ b,
                      const float* __restrict__ c, const float* __restrict__ dd,
                      u16* __restrict__ oa, u16* __restrict__ ob,
                      u16* __restrict__ oc, u16* __restrict__ od) {
  int y = blockIdx.y;
  const float* s = (y == 0) ? a : (y == 1) ? b : (y == 2) ? c : dd;
  u16* d = (y == 0) ? oa : (y == 1) ? ob : (y == 2) ? oc : od;
  int i = blockIdx.x * 256 + threadIdx.x;
  f32x4 v = ((const f32x4*)s)[i];
  u16x4 r;
#pragma unroll
  for (int j = 0; j < 4; ++j) r[j] = f2bf(v[j]);
  ((u16x4*)d)[i] = r;
}

// ---------------- mask bit-pack + transpose: [B,S,S] i32 -> MP[b][kt][q] u32x2 ----------------
__global__ void pack_mask(const int* __restrict__ m, u32* __restrict__ mp) {
  int tid = blockIdx.x * 256 + threadIdx.x;  // 131072 = 2*32*2048
  int q = tid & 2047, kt = (tid >> 11) & 31, b = tid >> 16;
  const i32x4* src = (const i32x4*)(m + ((size_t)(b * 2048 + q)) * 2048 + kt * 64);
  u32 w0 = 0, w1 = 0;
#pragma unroll
  for (int j = 0; j < 8; ++j) {
    i32x4 a = src[j], c = src[j + 8];
#pragma unroll
    for (int e = 0; e < 4; ++e) {
      w0 |= (a[e] != 0 ? 1u : 0u) << (j * 4 + e);
      w1 |= (c[e] != 0 ? 1u : 0u) << (j * 4 + e);
    }
  }
  ((u32x2*)mp)[((size_t)(b * 32 + kt)) * 2048 + q] = u32x2{w0, w1};
}

// ---------------- QKV GEMM (R14 + 3 blocks/CU): A fp32 via global_load_lds ----------------
__global__ __launch_bounds__(256, 3) void gemm_qkv(const float* __restrict__ Aq,
                                                   const float* __restrict__ Ak,
                                                   const float* __restrict__ Av,
                                                   const u16* __restrict__ Wb,
                                                   u16* __restrict__ out) {
  __shared__ alignas(16) char lds[49152];
  const int t = threadIdx.x;
  const int lane = t & 63, wid = t >> 6;
  const int g = lane >> 4, r16 = lane & 15;
  const int wm = wid >> 1, wn = wid & 1;
  const int m0 = blockIdx.x * 128, n0 = blockIdx.y * 128;
  const int z = blockIdx.z;

  const float* Axf = (z == 0) ? Aq : (z == 1) ? Ak : Av;
  const char* Ab = (const char*)Axf;
  const char* Bb = (const char*)(Wb + (size_t)z * 1048576);
  u16* op = out + (size_t)z * 4194304;
  const float qsc = (z == 0) ? 0.18033688011f : 1.0f;  // 0.125*log2(e) into Q

  f32x4 acc[4][4] = {};

  for (int kk = 0; kk < 1024; kk += 64) {
#pragma unroll
    for (int i = 0; i < 8; ++i) {
      int ci = i * 256 + t;          // 16B slot
      int row = ci >> 4;
      int pc = ci & 15;
      int lc = pc ^ (row & 15);
      gload_lds16(Ab + (size_t)(m0 + row) * 4096 + kk * 4 + lc * 16, lds + ci * 16);
    }
#pragma unroll
    for (int i = 0; i < 4; ++i) {
      int ci = i * 256 + t;
      int row = ci >> 3;
      int cbs = ((ci & 7) << 4) ^ ((row & 7) << 4);
      gload_lds16(Bb + (size_t)(n0 + row) * 2048 + kk * 2 + cbs, lds + 32768 + ci * 16);
    }
    __syncthreads();
#pragma unroll
    for (int kc = 0; kc < 2; ++kc) {
      bf16x8 af[4], bfr[4];
#pragma unroll
      for (int mf = 0; mf < 4; ++mf) {
        int row = wm * 64 + mf * 16 + r16;
        const char* arow = lds + row * 256;
        int x = row & 15;
        int lc0 = 8 * kc + 2 * g;    // logical 16B chunk of k = 32kc+8g
        f32x4 alo = *(const f32x4*)(arow + ((lc0 ^ x) * 16));
        f32x4 ahi = *(const f32x4*)(arow + (((lc0 + 1) ^ x) * 16));
        u16x8 pk;
#pragma unroll
        for (int j = 0; j < 4; ++j) { pk[j] = f2bf(alo[j]); pk[4 + j] = f2bf(ahi[j]); }
        af[mf] = __builtin_bit_cast(bf16x8, pk);
      }
#pragma unroll
      for (int nf = 0; nf < 4; ++nf) {
        int row = wn * 64 + nf * 16 + r16;
        bfr[nf] = *(const bf16x8*)(lds + 32768 + row * 128 +
                                   ((64 * kc + 16 * g) ^ ((row & 7) << 4)));
      }
#pragma unroll
      for (int mf = 0; mf < 4; ++mf)
#pragma unroll
        for (int nf = 0; nf < 4; ++nf)
          acc[mf][nf] = __builtin_amdgcn_mfma_f32_16x16x32_bf16(af[mf], bfr[nf], acc[mf][nf], 0, 0, 0);
    }
    __syncthreads();
  }

#pragma unroll
  for (int mf = 0; mf < 4; ++mf) {
#pragma unroll
    for (int nf = 0; nf < 4; ++nf) {
      int mb = m0 + wm * 64 + mf * 16 + 4 * g;
      int n = n0 + wn * 64 + nf * 16 + r16;
      if (z == 0) {  // Q: [B,H,S,DK] bf16, pre-scaled
        int bb = mb >> 11, h = n >> 6, dk = n & 63;
#pragma unroll
        for (int r = 0; r < 4; ++r) {
          int s2 = (mb + r) & 2047;
          op[((size_t)(bb * 16 + h) * 2048 + s2) * 64 + dk] = f2bf(acc[mf][nf][r] * qsc);
        }
      } else if (z == 1) {  // K packed: KP[bh][kt][half][chunk][l31] x16B
        int h = n >> 6, dk = n & 63;
#pragma unroll
        for (int r = 0; r < 4; ++r) {
          int m = mb + r;
          int bb = m >> 11, s2 = m & 2047;
          size_t off16 = ((((size_t)(bb * 16 + h) * 32 + (s2 >> 6)) * 2 + ((s2 >> 5) & 1)) * 8 +
                          (dk >> 3)) * 32 + (s2 & 31);
          op[off16 * 8 + (dk & 7)] = f2bf(acc[mf][nf][r]);
        }
      } else {  // V packed: VP[bh][kt][chunk][db][l31] x16B
        int bb = mb >> 11, s2 = mb & 2047, h = n >> 6, d = n & 63;
        size_t off16 = ((((size_t)(bb * 16 + h) * 32 + (s2 >> 6)) * 8 + ((s2 & 63) >> 3)) * 2 +
                        (d >> 5)) * 32 + (d & 31);
        u16x4 pv;
#pragma unroll
        for (int r = 0; r < 4; ++r) pv[r] = f2bf(acc[mf][nf][r]);
        *(u16x4*)(op + off16 * 8 + (s2 & 7)) = pv;
      }
    }
  }
}

// ---------------- out-projection GEMM: bf16 A (ctx), fp32 output ----------------
__global__ __launch_bounds__(256, 2) void gemm_out(const u16* __restrict__ X,
                                                   const u16* __restrict__ W,
                                                   float* __restrict__ out) {
  __shared__ alignas(16) char lds[32768];
  const int t = threadIdx.x;
  const int lane = t & 63, wid = t >> 6;
  const int g = lane >> 4, r16 = lane & 15;
  const int wm = wid >> 1, wn = wid & 1;
  const int m0 = blockIdx.x * 128, n0 = blockIdx.y * 128;
  const char* Ab = (const char*)X;
  const char* Bb = (const char*)W;

  f32x4 acc[4][4] = {};

  for (int kk = 0; kk < 1024; kk += 64) {
#pragma unroll
    for (int i = 0; i < 4; ++i) {
      int ci = i * 256 + t;
      int row = ci >> 3;
      int cbs = ((ci & 7) << 4) ^ ((row & 7) << 4);
      gload_lds16(Ab + (size_t)(m0 + row) * 2048 + kk * 2 + cbs, lds + ci * 16);
      gload_lds16(Bb + (size_t)(n0 + row) * 2048 + kk * 2 + cbs, lds + 16384 + ci * 16);
    }
    __syncthreads();
#pragma unroll
    for (int kc = 0; kc < 2; ++kc) {
      bf16x8 af[4], bfr[4];
#pragma unroll
      for (int mf = 0; mf < 4; ++mf) {
        int row = wm * 64 + mf * 16 + r16;
        af[mf] = *(const bf16x8*)(lds + row * 128 + ((64 * kc + 16 * g) ^ ((row & 7) << 4)));
      }
#pragma unroll
      for (int nf = 0; nf < 4; ++nf) {
        int row = wn * 64 + nf * 16 + r16;
        bfr[nf] = *(const bf16x8*)(lds + 16384 + row * 128 + ((64 * kc + 16 * g) ^ ((row & 7) << 4)));
      }
#pragma unroll
      for (int mf = 0; mf < 4; ++mf)
#pragma unroll
        for (int nf = 0; nf < 4; ++nf)
          acc[mf][nf] = __builtin_amdgcn_mfma_f32_16x16x32_bf16(af[mf], bfr[nf], acc[mf][nf], 0, 0, 0);
    }
    __syncthreads();
  }

#pragma unroll
  for (int mf = 0; mf < 4; ++mf)
#pragma unroll
    for (int nf = 0; nf < 4; ++nf) {
      int mb = m0 + wm * 64 + mf * 16 + 4 * g;
      int n = n0 + wn * 64 + nf * 16 + r16;
#pragma unroll
      for (int r = 0; r < 4; ++r) out[(size_t)(mb + r) * 1024 + n] = acc[mf][nf][r];
    }
}

// ---------------- flash attention: R9-exact (proven 60us / absmax 2e-3) ----------------
struct KF { bf16x8 k0[4], k1[4]; };

__device__ __forceinline__ void loadK(KF& f, const char* p) {
#pragma unroll
  for (int c = 0; c < 4; ++c) {
    f.k0[c] = *(const bf16x8*)(p + c * 1024);
    f.k1[c] = *(const bf16x8*)(p + 4096 + c * 1024);
  }
}

__device__ __forceinline__ void attn_body(const bf16x8 (&qf)[4], KF& cur, KF& nxt,
                                          const char*& kp, const char*& vp0,
                                          const char*& vp1, const u32x2*& mptr,
                                          u32x2& mcur, int hi,
                                          f32x16& o0, f32x16& o1, float& l_run) {
  bf16x8 v0[4], v1[4];
#pragma unroll
  for (int ks = 0; ks < 4; ++ks) {
    v0[ks] = *(const bf16x8*)(vp0 + ks * 2048);
    v1[ks] = *(const bf16x8*)(vp1 + ks * 2048);
  }
  loadK(nxt, kp);
  u32x2 mnext = *mptr;
  kp += 8192; vp0 += 8192; vp1 += 8192; mptr += 2048;
  __builtin_amdgcn_sched_barrier(0);

  f32x16 s0 = {}, s1 = {};
#pragma unroll
  for (int c = 0; c < 4; ++c) {
    s0 = __builtin_amdgcn_mfma_f32_32x32x16_bf16(cur.k0[c], qf[c], s0, 0, 0, 0);
    s1 = __builtin_amdgcn_mfma_f32_32x32x16_bf16(cur.k1[c], qf[c], s1, 0, 0, 0);
  }

  u32 wa = mcur.x >> (4 * hi), wb = mcur.y >> (4 * hi);
  float ps = 0.f;
#pragma unroll
  for (int r = 0; r < 16; ++r) {
    const int bit = (r & 3) + 8 * (r >> 2);
    float p0 = __builtin_amdgcn_exp2f(s0[r]);
    float p1 = __builtin_amdgcn_exp2f(s1[r]);
    int sm0 = ((int)(wa << (31 - bit))) >> 31;
    int sm1 = ((int)(wb << (31 - bit))) >> 31;
    p0 = __uint_as_float(__float_as_uint(p0) & (u32)sm0);
    p1 = __uint_as_float(__float_as_uint(p1) & (u32)sm1);
    s0[r] = p0; s1[r] = p1;
    ps += p0 + p1;
  }
  l_run += ps;

  u32 w[16];
#pragma unroll
  for (int kb = 0; kb < 2; ++kb) {
#pragma unroll
    for (int ss = 0; ss < 2; ++ss) {
      const f32x16& sp = kb ? s1 : s0;
      u32 A0, B0, A1, B1;
      asm("v_cvt_pk_bf16_f32 %0, %1, %2" : "=v"(A0) : "v"(sp[8*ss+0]), "v"(sp[8*ss+1]));
      asm("v_cvt_pk_bf16_f32 %0, %1, %2" : "=v"(B0) : "v"(sp[8*ss+2]), "v"(sp[8*ss+3]));
      asm("v_cvt_pk_bf16_f32 %0, %1, %2" : "=v"(A1) : "v"(sp[8*ss+4]), "v"(sp[8*ss+5]));
      asm("v_cvt_pk_bf16_f32 %0, %1, %2" : "=v"(B1) : "v"(sp[8*ss+6]), "v"(sp[8*ss+7]));
      asm("v_permlane32_swap_b32 %0, %1" : "+v"(A0), "+v"(A1));
      asm("v_permlane32_swap_b32 %0, %1" : "+v"(B0), "+v"(B1));
      int f = 2 * kb + ss;
      w[4*f+0] = A0; w[4*f+1] = B0; w[4*f+2] = A1; w[4*f+3] = B1;
    }
  }

#pragma unroll
  for (int ks = 0; ks < 4; ++ks) {
    bf16x8 pa = __builtin_bit_cast(bf16x8, u32x4{w[4*ks], w[4*ks+1], w[4*ks+2], w[4*ks+3]});
    o0 = __builtin_amdgcn_mfma_f32_32x32x16_bf16(pa, v0[ks], o0, 0, 0, 0);
    o1 = __builtin_amdgcn_mfma_f32_32x32x16_bf16(pa, v1[ks], o1, 0, 0, 0);
  }
  mcur = mnext;
}

__global__ __launch_bounds__(256, 2) void attn_kern(const u16* __restrict__ Qh,
                                                    const u16* __restrict__ Kh,
                                                    const u16* __restrict__ Vt,
                                                    const u32* __restrict__ mp,
                                                    u16* __restrict__ ctx) {
  __shared__ float cmb[2][32][64];
  __shared__ float cmbl[2][64];
  const int t = threadIdx.x;
  const int wid = t >> 6, lane = t & 63;
  const int qw = wid & 1, kh = wid >> 1;
  const int hi = lane >> 5, l31 = lane & 31;

  const int wg = (blockIdx.x & 7) * 128 + (blockIdx.x >> 3);
  const int qt = wg & 31, bh = wg >> 5;
  const int b = bh >> 4, h = bh & 15;

  const char* qbytes = (const char*)Qh;
  const int qbase = qt * 64 + qw * 32;
  const int qg = qbase + l31;

  bf16x8 qf[4];
#pragma unroll
  for (int c = 0; c < 4; ++c)
    qf[c] = *(const bf16x8*)(qbytes + ((size_t)bh * 2048 + qg) * 128 + 32 * c + 16 * hi);

  const char* kp  = (const char*)Kh + (size_t)bh * 262144 + (size_t)kh * 131072 + hi * 512 + l31 * 16;
  const char* vp0 = (const char*)Vt + (size_t)bh * 262144 + (size_t)kh * 131072 + hi * 1024 + l31 * 16;
  const char* vp1 = vp0 + 512;
  const u32x2* mptr = (const u32x2*)mp + (size_t)b * 65536 + (size_t)kh * 32768 + qg;

  f32x16 o0 = {}, o1 = {};
  float l_run = 0.f;

  KF A, B2;
  loadK(A, kp);
  kp += 8192;
  u32x2 mcur = *mptr;
  mptr += 2048;

#pragma unroll 1
  for (int it = 0; it < 8; ++it) {
    attn_body(qf, A, B2, kp, vp0, vp1, mptr, mcur, hi, o0, o1, l_run);
    attn_body(qf, B2, A, kp, vp0, vp1, mptr, mcur, hi, o0, o1, l_run);
  }

  l_run += __shfl_xor(l_run, 32, 64);

  if (kh) {
#pragma unroll
    for (int r = 0; r < 16; ++r) {
      cmb[qw][r][lane]      = o0[r];
      cmb[qw][16 + r][lane] = o1[r];
    }
    cmbl[qw][lane] = l_run;
  }
  __syncthreads();
  if (!kh) {
#pragma unroll
    for (int r = 0; r < 16; ++r) {
      o0[r] += cmb[qw][r][lane];
      o1[r] += cmb[qw][16 + r][lane];
    }
    l_run += cmbl[qw][lane];

    float rl = 1.f / l_run;
#pragma unroll
    for (int r = 0; r < 16; ++r) {
      float rv = __shfl(rl, (r & 3) + 8 * (r >> 2) + 4 * hi, 64);
      int q = qbase + (r & 3) + 8 * (r >> 2) + 4 * hi;
      size_t rowp = ((size_t)b * 2048 + q) * 1024 + h * 64 + l31;
      ctx[rowp]      = f2bf(o0[r] * rv);
      ctx[rowp + 32] = f2bf(o1[r] * rv);
    }
  }
}

// ---------------- launch ----------------
extern "C" void kernel_launch(void* const* d_in, const int* in_sizes, int n_in,
                              void* d_out, int out_size, void* d_ws, size_t ws_size,
                              hipStream_t stream) {
  const float* q  = (const float*)d_in[0];
  const float* k  = (const float*)d_in[1];
  const float* v  = (const float*)d_in[2];
  const int* mask = (const int*)d_in[3];
  const float* Wq = (const float*)d_in[4];
  const float* Wk = (const float*)d_in[5];
  const float* Wv = (const float*)d_in[6];
  const float* Wo = (const float*)d_in[7];

  u16* ws = (u16*)d_ws;
  const size_t NX = (size_t)4096 * 1024;
  const size_t NW = (size_t)1024 * 1024;
  u16* Wqb = ws + 3 * NX;
  u16* Qh  = Wqb + 4 * NW;          // Qh | KP | VP consecutive
  u16* ctx = Qh + 3 * NX;
  u32* mpk = (u32*)ws;              // 1 MB

  cvt_w<<<dim3(1024, 4), 256, 0, stream>>>(Wq, Wk, Wv, Wo,
                                           Wqb, Wqb + NW, Wqb + 2 * NW, Wqb + 3 * NW);
  pack_mask<<<dim3(512), 256, 0, stream>>>(mask, mpk);
  gemm_qkv<<<dim3(32, 8, 3), 256, 0, stream>>>(q, k, v, Wqb, Qh);
  attn_kern<<<dim3(1024), 256, 0, stream>>>(Qh, Qh + NX, Qh + 2 * NX, mpk, ctx);
  gemm_out<<<dim3(32, 8), 256, 0, stream>>>(ctx, Wqb + 3 * NW, (float*)d_out);
}